// Round 1
// baseline (52.531 us; speedup 1.0000x reference)
//
#include <hip/hip_runtime.h>
#include <hip/hip_bf16.h>
#include <math.h>

#define BB 256
#define NN 50
#define DD 128
#define HS 130          // h row stride in floats: +2 pad (keeps 8B align, breaks bank-0 alignment of rows)
#define MAXA 2000
#define NEGV -9e15f

struct __align__(8) f2 { float x, y; };

__global__ __launch_bounds__(256) void sg_fused_kernel(
    const int* __restrict__ inputs,      // [B,N]
    const int* __restrict__ adj,         // [B,N,N]
    const float* __restrict__ A_attr,    // [B,MAXA]
    const float* __restrict__ embedding, // [N_NODE,D]
    const float* __restrict__ attr_emb,  // [MAXA,D]
    const float* __restrict__ a0,
    const float* __restrict__ a1,
    const float* __restrict__ a2,
    const float* __restrict__ a3,
    float* __restrict__ out,             // [B,N,D]
    float* __restrict__ attr_out)        // [B,D]
{
    const int blk = blockIdx.x;
    const int tid = threadIdx.x;

    if (blk < BB) {
        // ------------------- GAT part: one block per batch b -------------------
        __shared__ float h[NN * HS];
        __shared__ float av[4 * HS];
        __shared__ float alpha[NN * NN];
        const int b = blk;

        // stage a0..a3 into LDS
        if (tid < DD) {
            av[0 * HS + tid] = a0[tid];
            av[1 * HS + tid] = a1[tid];
            av[2 * HS + tid] = a2[tid];
            av[3 * HS + tid] = a3[tid];
        }
        // stage h = embedding[inputs[b]] as float2: 50*64 = 3200 float2
        for (int idx = tid; idx < NN * DD / 2; idx += 256) {
            const int i  = idx >> 6;   // row 0..49
            const int d2 = idx & 63;   // float2 index 0..63
            const int node = inputs[b * NN + i];
            const f2 v = *(const f2*)(embedding + node * DD + d2 * 2);
            *(f2*)(h + i * HS + d2 * 2) = v;
        }
        __syncthreads();

        // scores + in-register softmax: wave per row i, lane per column j
        const int wave = tid >> 6;
        const int lane = tid & 63;
        for (int i = wave; i < NN; i += 4) {
            float e = -INFINITY;  // pad lanes contribute exp()=0
            if (lane < NN) {
                const int a = adj[(b * NN + i) * NN + lane];
                if (a == 0) {
                    e = NEGV;
                } else {
                    const float* as = av + (a - 1) * HS;
                    const float* hi = h + i * HS;
                    const float* hj = h + lane * HS;
                    float acc = 0.f;
                    #pragma unroll 8
                    for (int d = 0; d < DD; d += 2) {
                        const f2 x  = *(const f2*)(hi + d);
                        const f2 y  = *(const f2*)(hj + d);
                        const f2 aa = *(const f2*)(as + d);
                        float p0 = x.x * y.x;
                        float p1 = x.y * y.y;
                        p0 = fmaxf(p0, 0.2f * p0);   // leaky_relu, alpha=0.2
                        p1 = fmaxf(p1, 0.2f * p1);
                        acc = fmaf(p0, aa.x, acc);
                        acc = fmaf(p1, aa.y, acc);
                    }
                    e = acc;
                }
            }
            // wave-wide softmax over the 50 valid lanes
            float m = e;
            for (int off = 32; off; off >>= 1)
                m = fmaxf(m, __shfl_xor(m, off));
            const float ex = (lane < NN) ? __expf(e - m) : 0.f;
            float s = ex;
            for (int off = 32; off; off >>= 1)
                s += __shfl_xor(s, off);
            if (lane < NN) alpha[i * NN + lane] = ex / s;
        }
        __syncthreads();

        // output = alpha @ h : 3200 float2 outputs
        for (int idx = tid; idx < NN * DD / 2; idx += 256) {
            const int i  = idx >> 6;
            const int d2 = idx & 63;
            float accx = 0.f, accy = 0.f;
            const float* al = alpha + i * NN;
            #pragma unroll 5
            for (int j = 0; j < NN; ++j) {
                const f2 hv = *(const f2*)(h + j * HS + d2 * 2);
                const float w = al[j];
                accx = fmaf(w, hv.x, accx);
                accy = fmaf(w, hv.y, accy);
            }
            f2 o; o.x = accx; o.y = accy;
            *(f2*)(out + (b * NN + i) * DD + d2 * 2) = o;
        }
    } else {
        // --------------- attr_sess = A_attr @ attr_emb : 2 b-rows per block ---------------
        __shared__ float red[2 * 2 * DD];   // [kh][r][d]
        const int b0 = (blk - BB) * 2;
        const int d  = tid & 127;
        const int kh = tid >> 7;
        float acc0 = 0.f, acc1 = 0.f;
        const float* Ar0 = A_attr + (size_t)(b0 + 0) * MAXA;
        const float* Ar1 = A_attr + (size_t)(b0 + 1) * MAXA;
        const int k0 = kh * (MAXA / 2);
        for (int k = k0; k < k0 + MAXA / 2; ++k) {
            const float ev = attr_emb[k * DD + d];   // coalesced; A reads are wave-uniform (scalar path)
            acc0 = fmaf(Ar0[k], ev, acc0);
            acc1 = fmaf(Ar1[k], ev, acc1);
        }
        red[(kh * 2 + 0) * DD + d] = acc0;
        red[(kh * 2 + 1) * DD + d] = acc1;
        __syncthreads();
        if (tid < 2 * DD) {
            const int r  = tid >> 7;
            const int dd = tid & 127;
            attr_out[(b0 + r) * DD + dd] =
                red[(0 * 2 + r) * DD + dd] + red[(1 * 2 + r) * DD + dd];
        }
    }
}

extern "C" void kernel_launch(void* const* d_in, const int* in_sizes, int n_in,
                              void* d_out, int out_size, void* d_ws, size_t ws_size,
                              hipStream_t stream) {
    const int*   inputs    = (const int*)  d_in[0];
    const int*   adj       = (const int*)  d_in[1];
    // d_in[2] = mask_item (unused by the reference)
    const float* A_attr    = (const float*)d_in[3];
    const float* embedding = (const float*)d_in[4];
    const float* attr_emb  = (const float*)d_in[5];
    const float* a0        = (const float*)d_in[6];
    const float* a1        = (const float*)d_in[7];
    const float* a2        = (const float*)d_in[8];
    const float* a3        = (const float*)d_in[9];

    float* out      = (float*)d_out;                 // [B,N,D] flat
    float* attr_out = out + (size_t)BB * NN * DD;    // [B,D] flat, concatenated

    const int grid = BB + BB / 2;  // 256 GAT blocks + 128 attr blocks
    sg_fused_kernel<<<grid, 256, 0, stream>>>(inputs, adj, A_attr, embedding,
                                              attr_emb, a0, a1, a2, a3,
                                              out, attr_out);
}